// Round 3
// baseline (1131.027 us; speedup 1.0000x reference)
//
#include <hip/hip_runtime.h>
#include <hip/hip_fp16.h>

#define HID 1024
#define QCOLS 512
#define KP 2048   // physical K per operand: [hi(1024) | lo(1024)]
#define NT 48     // logical K' = 3072 = 48 tiles of 64

typedef _Float16 f16x8 __attribute__((ext_vector_type(8)));
typedef float f32x4 __attribute__((ext_vector_type(4)));

// ---- K0: transpose+convert+split: src[K][N] f32 -> dst[N][2K] f16 [hi|lo] ----
__global__ void tconv_split(const float* __restrict__ src, __half* __restrict__ dst,
                            int K, int N, float scale) {
  __shared__ float tile[32][33];
  int n0 = blockIdx.x * 32, k0 = blockIdx.y * 32;
  int tx = threadIdx.x, ty = threadIdx.y;
  for (int i = ty; i < 32; i += 8)
    tile[i][tx] = src[(size_t)(k0 + i) * N + n0 + tx];
  __syncthreads();
  for (int i = ty; i < 32; i += 8) {
    float v = tile[tx][i] * scale;
    __half h = __float2half(v);
    size_t o = (size_t)(n0 + i) * (2 * K) + k0 + tx;
    dst[o] = h;
    dst[o + K] = __float2half(v - __half2float(h));
  }
}

// ---- K1: h1 = relu(yA @ w1 + b1) fp32, split to [hi|lo] f16 (x64) ------------
__global__ __launch_bounds__(256)
void h1_split(const float* __restrict__ y, const float* __restrict__ w1,
              const float* __restrict__ b1, __half* __restrict__ h1,
              int row0, int nrows) {
  int idx = blockIdx.x * 256 + threadIdx.x;
  if (idx >= nrows * HID) return;
  int r = idx >> 10, c = idx & (HID - 1);
  const float* yr = y + (size_t)(row0 + r) * 17;
  float acc = b1[c];
#pragma unroll
  for (int k = 0; k < 8; ++k) acc = fmaf(yr[k], w1[k * HID + c], acc);
  float v = fmaxf(acc, 0.f) * 64.f;
  __half h = __float2half(v);
  size_t o = (size_t)r * KP + c;
  h1[o] = h;
  h1[o + 1024] = __float2half(v - __half2float(h));
}

// ---- 256x256 deep-pipelined split-f16 GEMM over logical K'=3072 --------------
// 512 threads = 8 waves (2M x 4N); per-wave C = 128x64; BK=64 as two K-halves.
// LDS per buffer: A_Ka | A_Kb | B_Ka | B_Kb (16KB planes), dbuf = 128KB.
// Plane layout: phys(row, slot q) = row*64 + (q ^ ((row>>1)&3))*16  (bank-free)
// Per phase: 12 ds_read_b128, stage next tile's same plane-pair (4 loads/thr),
// barrier, 32 MFMA (setprio), s_waitcnt vmcnt(4), barrier.  ACT 0: relu->split
// f16 [hi|lo] (x64); ACT 1: softplus -> f32.  acc scale 2^14.
template <int ACT>
__global__ __launch_bounds__(512, 2)
void gemm8p(const __half* __restrict__ A, const __half* __restrict__ B,
            const float* __restrict__ bias, __half* __restrict__ Co,
            float* __restrict__ Cf, int ldc) {
  __shared__ char lds[131072];
  const int tid = threadIdx.x;
  const int lane = tid & 63, wave = tid >> 6;
  const int p = lane & 15, ql = lane >> 4;
  const int wm = wave >> 2, wn = wave & 3;

  // XCD-bijective block swizzle (m204)
  const int gx = gridDim.x, nwg = gx * gridDim.y;
  const int bid = blockIdx.y * gx + blockIdx.x;
  const int q8 = nwg >> 3, r8 = nwg & 7;
  const int xcd = bid & 7, lxi = bid >> 3;
  const int swz = (xcd < r8 ? xcd * (q8 + 1) : r8 * (q8 + 1) + (xcd - r8) * q8) + lxi;
  const size_t row_blk = (size_t)(swz / gx) * 256;
  const size_t col_blk = (size_t)(swz % gx) * 256;

  // ds_read byte offsets within a 16KB plane
  int a_off[8], b_off[4];
#pragma unroll
  for (int m = 0; m < 8; ++m) {
    int r = wm * 128 + m * 16 + p;
    a_off[m] = r * 64 + ((ql ^ ((r >> 1) & 3)) << 4);
  }
#pragma unroll
  for (int n = 0; n < 4; ++n) {
    int r = wn * 64 + n * 16 + p;
    b_off[n] = r * 64 + ((ql ^ ((r >> 1) & 3)) << 4);
  }

  // staging slots (2 per plane per thread), pre-swizzled global source
  const int idx0 = tid, idx1 = tid + 512;
  const int sr0 = idx0 >> 2, sq0 = (idx0 & 3) ^ ((sr0 >> 1) & 3);
  const int sr1 = idx1 >> 2, sq1 = (idx1 & 3) ^ ((sr1 >> 1) & 3);

  auto stage = [&](int buf, int h, int kt) {
    const int lk = kt * 64;
    const int ak = ((lk >= 2048) ? 1024 : 0) + (lk & 1023) + h * 32;
    const int bk = ((lk >= 1024 && lk < 2048) ? 1024 : 0) + (lk & 1023) + h * 32;
    char* pa = lds + buf * 65536 + h * 16384;
    char* pb = pa + 32768;
    const __half* ga0 = A + (row_blk + sr0) * (size_t)KP + ak + sq0 * 8;
    const __half* ga1 = A + (row_blk + sr1) * (size_t)KP + ak + sq1 * 8;
    const __half* gb0 = B + (col_blk + sr0) * (size_t)KP + bk + sq0 * 8;
    const __half* gb1 = B + (col_blk + sr1) * (size_t)KP + bk + sq1 * 8;
    __builtin_amdgcn_global_load_lds((__attribute__((address_space(1))) void*)ga0,
        (__attribute__((address_space(3))) void*)(pa + idx0 * 16), 16, 0, 0);
    __builtin_amdgcn_global_load_lds((__attribute__((address_space(1))) void*)ga1,
        (__attribute__((address_space(3))) void*)(pa + idx1 * 16), 16, 0, 0);
    __builtin_amdgcn_global_load_lds((__attribute__((address_space(1))) void*)gb0,
        (__attribute__((address_space(3))) void*)(pb + idx0 * 16), 16, 0, 0);
    __builtin_amdgcn_global_load_lds((__attribute__((address_space(1))) void*)gb1,
        (__attribute__((address_space(3))) void*)(pb + idx1 * 16), 16, 0, 0);
  };

  // prologue: tile 0 fully staged, drained once
  stage(0, 0, 0);
  stage(0, 1, 0);
  asm volatile("s_waitcnt vmcnt(0)" ::: "memory");
  __builtin_amdgcn_s_barrier();

  f32x4 acc[8][4] = {};

  for (int t = 0; t < NT; ++t) {
    const int bufp = t & 1;
    const int ts = (t + 1 < NT) ? t + 1 : NT - 1;  // clamped dummy restage at end
#pragma unroll
    for (int h = 0; h < 2; ++h) {
      const char* pA = lds + bufp * 65536 + h * 16384;
      const char* pB = pA + 32768;
      f16x8 af[8], bfr[4];
#pragma unroll
      for (int m = 0; m < 8; ++m) af[m] = *(const f16x8*)(pA + a_off[m]);
#pragma unroll
      for (int n = 0; n < 4; ++n) bfr[n] = *(const f16x8*)(pB + b_off[n]);
      stage(bufp ^ 1, h, ts);
      __builtin_amdgcn_sched_barrier(0);
      __builtin_amdgcn_s_barrier();
      __builtin_amdgcn_sched_barrier(0);
      __builtin_amdgcn_s_setprio(1);
#pragma unroll
      for (int m = 0; m < 8; ++m)
#pragma unroll
        for (int n = 0; n < 4; ++n)
          acc[m][n] = __builtin_amdgcn_mfma_f32_16x16x32_f16(af[m], bfr[n], acc[m][n], 0, 0, 0);
      __builtin_amdgcn_s_setprio(0);
      asm volatile("s_waitcnt vmcnt(4)" ::: "memory");
      __builtin_amdgcn_sched_barrier(0);
      __builtin_amdgcn_s_barrier();
      __builtin_amdgcn_sched_barrier(0);
    }
  }

  // epilogue — C/D map: col = lane&15, row = (lane>>4)*4 + j  [verified]
  const float unscale = 1.f / 16384.f;
#pragma unroll
  for (int n = 0; n < 4; ++n) {
    const size_t col = col_blk + wn * 64 + n * 16 + p;
    const float bv = bias[col];
#pragma unroll
    for (int m = 0; m < 8; ++m) {
      const size_t row0 = row_blk + wm * 128 + m * 16 + ql * 4;
#pragma unroll
      for (int j = 0; j < 4; ++j) {
        float v = acc[m][n][j] * unscale + bv;
        const size_t o = (row0 + j) * (size_t)ldc + col;
        if constexpr (ACT == 0) {
          float r = fmaxf(v, 0.f) * 64.f;
          __half hh = __float2half(r);
          Co[o] = hh;
          Co[o + 1024] = __float2half(r - __half2float(hh));
        } else {
          float sp = fmaxf(v, 0.f) + log1pf(expf(-fabsf(v)));  // stable softplus
          Cf[o] = sp + 1e-6f;
        }
      }
    }
  }
}

// ---- K4: per-row piecewise-linear inverse + jacobian (np-order-matched) ------
__global__ __launch_bounds__(256)
void epilogue_kernel(const float* __restrict__ y, const float* __restrict__ q,
                     float* __restrict__ out, int row0, int nrows) {
  const int wave = threadIdx.x >> 6, lane = threadIdx.x & 63;
  const int r = blockIdx.x * 4 + wave;
  if (r >= nrows) return;
  const float* yr = y + (size_t)(row0 + r) * 17;
  float* orow = out + (size_t)(row0 + r) * 17;
  const float* qr = q + (size_t)r * QCOLS;
  float prod_inv = 1.f;
#pragma unroll
  for (int t = 0; t < 8; ++t) {
    const float qv = qr[t * 64 + lane];
    float s = qv;  // inclusive prefix sum over 64 lanes
#pragma unroll
    for (int d = 1; d < 64; d <<= 1) {
      float u = __shfl_up(s, d);
      if (lane >= d) s += u;
    }
    const float total = __shfl(s, 63);
    const float sn = s / total;
    const float dnorm = total * 0.015625f;
    const float slope_l = qv / dnorm;
    const float yb = yr[8 + t];
    const unsigned long long m = __ballot(sn < yb);
    int bin = (int)__popcll(m);
    bin = bin > 63 ? 63 : bin;
    const float off_g = __shfl(sn, bin > 0 ? bin - 1 : 0);
    const float off = (bin == 0) ? 0.f : off_g;
    const float sl = __shfl(slope_l, bin);
    const float xB = (yb - off) / sl + (float)bin * 0.015625f;
    if (lane == t) orow[8 + t] = xB;
    prod_inv *= (1.f / sl);
  }
  if (lane < 8) orow[lane] = yr[lane];
  if (lane == 8) orow[16] = yr[16] * prod_inv;
}

// ---- launch ------------------------------------------------------------------
extern "C" void kernel_launch(void* const* d_in, const int* in_sizes, int n_in,
                              void* d_out, int out_size, void* d_ws, size_t ws_size,
                              hipStream_t stream) {
  const float* y  = (const float*)d_in[0];
  const float* w1 = (const float*)d_in[1];
  const float* b1 = (const float*)d_in[2];
  const float* w2 = (const float*)d_in[3];
  const float* b2 = (const float*)d_in[4];
  const float* w3 = (const float*)d_in[5];
  const float* b3 = (const float*)d_in[6];
  float* out = (float*)d_out;
  const long Btot = in_sizes[0] / 17;

  char* ws = (char*)d_ws;
  __half* w2t = (__half*)ws;                      // 4 MB  [1024][2048] hi|lo
  __half* w3t = (__half*)(ws + (4u << 20));       // 2 MB  [512][2048]  hi|lo
  const size_t fixed = (size_t)6 << 20;

  // per-row scratch: h1' 4KB + h2' 4KB ; q (f32 2KB) aliases h1' region
  size_t avail = ws_size > fixed ? ws_size - fixed : 0;
  long maxrows = (long)(avail / 8192);
  long chunk = Btot < maxrows ? Btot : maxrows;
  chunk &= ~255L;
  if (chunk < 256) chunk = 256;

  __half* h1buf = (__half*)(ws + fixed);
  __half* h2buf = (__half*)(ws + fixed + (size_t)chunk * 4096);
  float* qbuf = (float*)h1buf;

  dim3 tb(32, 8);
  tconv_split<<<dim3(HID / 32, HID / 32), tb, 0, stream>>>(w2, w2t, HID, HID, 256.f);
  tconv_split<<<dim3(QCOLS / 32, HID / 32), tb, 0, stream>>>(w3, w3t, HID, QCOLS, 256.f);

  for (long row0 = 0; row0 < Btot; row0 += chunk) {
    const int nr = (int)((Btot - row0 < chunk) ? (Btot - row0) : chunk);
    h1_split<<<nr * (HID / 256), 256, 0, stream>>>(y, w1, b1, h1buf, (int)row0, nr);
    gemm8p<0><<<dim3(HID / 256, nr / 256), 512, 0, stream>>>(h1buf, w2t, b2, h2buf, nullptr, KP);
    gemm8p<1><<<dim3(QCOLS / 256, nr / 256), 512, 0, stream>>>(h2buf, w3t, b3, nullptr, qbuf, QCOLS);
    epilogue_kernel<<<(nr + 3) / 4, 256, 0, stream>>>(y, qbuf, out, (int)row0, nr);
  }
}

// Round 4
// 1081.147 us; speedup vs baseline: 1.0461x; 1.0461x over previous
//
#include <hip/hip_runtime.h>
#include <hip/hip_fp16.h>

#define HID 1024
#define QCOLS 512
#define KP 2048   // physical K per operand: [hi(1024) | lo(1024)]
#define NT 48     // logical K' = 3072 = 48 tiles of 64

typedef _Float16 f16x8 __attribute__((ext_vector_type(8)));
typedef float f32x4 __attribute__((ext_vector_type(4)));

// ---- K0: transpose+convert+split: src[K][N] f32 -> dst[N][2K] f16 [hi|lo] ----
__global__ void tconv_split(const float* __restrict__ src, __half* __restrict__ dst,
                            int K, int N, float scale) {
  __shared__ float tile[32][33];
  int n0 = blockIdx.x * 32, k0 = blockIdx.y * 32;
  int tx = threadIdx.x, ty = threadIdx.y;
  for (int i = ty; i < 32; i += 8)
    tile[i][tx] = src[(size_t)(k0 + i) * N + n0 + tx];
  __syncthreads();
  for (int i = ty; i < 32; i += 8) {
    float v = tile[tx][i] * scale;
    __half h = __float2half(v);
    size_t o = (size_t)(n0 + i) * (2 * K) + k0 + tx;
    dst[o] = h;
    dst[o + K] = __float2half(v - __half2float(h));
  }
}

// ---- K1: h1 = relu(yA @ w1 + b1) fp32, split to [hi|lo] f16 (x64), vectorized -
__global__ __launch_bounds__(256)
void h1_split_v2(const float* __restrict__ y, const float* __restrict__ w1,
                 const float* __restrict__ b1, __half* __restrict__ h1,
                 int row0, int nrows) {
  const int t = threadIdx.x & 127;   // 128 col-groups of 8
  const int rl = threadIdx.x >> 7;   // 2 rows per block
  const long r = (long)blockIdx.x * 2 + rl;
  if (r >= nrows) return;
  const float* yr = y + (size_t)(row0 + r) * 17;
  float yv[8];
#pragma unroll
  for (int k = 0; k < 8; ++k) yv[k] = yr[k];
  const int c0 = t * 8;
  f32x4 a0 = *(const f32x4*)(b1 + c0);
  f32x4 a1 = *(const f32x4*)(b1 + c0 + 4);
#pragma unroll
  for (int k = 0; k < 8; ++k) {
    const f32x4 w0 = *(const f32x4*)(w1 + k * HID + c0);
    const f32x4 w1v = *(const f32x4*)(w1 + k * HID + c0 + 4);
#pragma unroll
    for (int j = 0; j < 4; ++j) {
      a0[j] = fmaf(yv[k], w0[j], a0[j]);
      a1[j] = fmaf(yv[k], w1v[j], a1[j]);
    }
  }
  f16x8 hi, lo;
#pragma unroll
  for (int j = 0; j < 8; ++j) {
    float v = fmaxf(j < 4 ? a0[j] : a1[j - 4], 0.f) * 64.f;
    _Float16 h = (_Float16)v;
    hi[j] = h;
    lo[j] = (_Float16)(v - (float)h);
  }
  *(f16x8*)(h1 + (size_t)r * KP + c0) = hi;
  *(f16x8*)(h1 + (size_t)r * KP + c0 + 1024) = lo;
}

// ---- 256x256 deep-pipelined split-f16 GEMM over logical K'=3072 --------------
// (identical schedule to round 3 — at 97% of 16x16x32-f16 ubench rate)
template <int ACT>
__device__ __forceinline__
void gemm8p_body(const __half* __restrict__ A, const __half* __restrict__ B,
                 const float* __restrict__ bias, __half* __restrict__ Co,
                 float* __restrict__ Cf, int ldc) {
  __shared__ char lds[131072];
  const int tid = threadIdx.x;
  const int lane = tid & 63, wave = tid >> 6;
  const int p = lane & 15, ql = lane >> 4;
  const int wm = wave >> 2, wn = wave & 3;

  // XCD-bijective block swizzle (m204)
  const int gx = gridDim.x, nwg = gx * gridDim.y;
  const int bid = blockIdx.y * gx + blockIdx.x;
  const int q8 = nwg >> 3, r8 = nwg & 7;
  const int xcd = bid & 7, lxi = bid >> 3;
  const int swz = (xcd < r8 ? xcd * (q8 + 1) : r8 * (q8 + 1) + (xcd - r8) * q8) + lxi;
  const size_t row_blk = (size_t)(swz / gx) * 256;
  const size_t col_blk = (size_t)(swz % gx) * 256;

  int a_off[8], b_off[4];
#pragma unroll
  for (int m = 0; m < 8; ++m) {
    int r = wm * 128 + m * 16 + p;
    a_off[m] = r * 64 + ((ql ^ ((r >> 1) & 3)) << 4);
  }
#pragma unroll
  for (int n = 0; n < 4; ++n) {
    int r = wn * 64 + n * 16 + p;
    b_off[n] = r * 64 + ((ql ^ ((r >> 1) & 3)) << 4);
  }

  const int idx0 = tid, idx1 = tid + 512;
  const int sr0 = idx0 >> 2, sq0 = (idx0 & 3) ^ ((sr0 >> 1) & 3);
  const int sr1 = idx1 >> 2, sq1 = (idx1 & 3) ^ ((sr1 >> 1) & 3);

  auto stage = [&](int buf, int h, int kt) {
    const int lk = kt * 64;
    const int ak = ((lk >= 2048) ? 1024 : 0) + (lk & 1023) + h * 32;
    const int bk = ((lk >= 1024 && lk < 2048) ? 1024 : 0) + (lk & 1023) + h * 32;
    char* pa = lds + buf * 65536 + h * 16384;
    char* pb = pa + 32768;
    const __half* ga0 = A + (row_blk + sr0) * (size_t)KP + ak + sq0 * 8;
    const __half* ga1 = A + (row_blk + sr1) * (size_t)KP + ak + sq1 * 8;
    const __half* gb0 = B + (col_blk + sr0) * (size_t)KP + bk + sq0 * 8;
    const __half* gb1 = B + (col_blk + sr1) * (size_t)KP + bk + sq1 * 8;
    __builtin_amdgcn_global_load_lds((__attribute__((address_space(1))) void*)ga0,
        (__attribute__((address_space(3))) void*)(pa + idx0 * 16), 16, 0, 0);
    __builtin_amdgcn_global_load_lds((__attribute__((address_space(1))) void*)ga1,
        (__attribute__((address_space(3))) void*)(pa + idx1 * 16), 16, 0, 0);
    __builtin_amdgcn_global_load_lds((__attribute__((address_space(1))) void*)gb0,
        (__attribute__((address_space(3))) void*)(pb + idx0 * 16), 16, 0, 0);
    __builtin_amdgcn_global_load_lds((__attribute__((address_space(1))) void*)gb1,
        (__attribute__((address_space(3))) void*)(pb + idx1 * 16), 16, 0, 0);
  };

  stage(0, 0, 0);
  stage(0, 1, 0);
  asm volatile("s_waitcnt vmcnt(0)" ::: "memory");
  __builtin_amdgcn_s_barrier();

  f32x4 acc[8][4] = {};

  for (int t = 0; t < NT; ++t) {
    const int bufp = t & 1;
    const int ts = (t + 1 < NT) ? t + 1 : NT - 1;
#pragma unroll
    for (int h = 0; h < 2; ++h) {
      const char* pA = lds + bufp * 65536 + h * 16384;
      const char* pB = pA + 32768;
      f16x8 af[8], bfr[4];
#pragma unroll
      for (int m = 0; m < 8; ++m) af[m] = *(const f16x8*)(pA + a_off[m]);
#pragma unroll
      for (int n = 0; n < 4; ++n) bfr[n] = *(const f16x8*)(pB + b_off[n]);
      stage(bufp ^ 1, h, ts);
      __builtin_amdgcn_sched_barrier(0);
      __builtin_amdgcn_s_barrier();
      __builtin_amdgcn_sched_barrier(0);
      __builtin_amdgcn_s_setprio(1);
#pragma unroll
      for (int m = 0; m < 8; ++m)
#pragma unroll
        for (int n = 0; n < 4; ++n)
          acc[m][n] = __builtin_amdgcn_mfma_f32_16x16x32_f16(af[m], bfr[n], acc[m][n], 0, 0, 0);
      __builtin_amdgcn_s_setprio(0);
      asm volatile("s_waitcnt vmcnt(4)" ::: "memory");
      __builtin_amdgcn_sched_barrier(0);
      __builtin_amdgcn_s_barrier();
      __builtin_amdgcn_sched_barrier(0);
    }
  }

  const float unscale = 1.f / 16384.f;
#pragma unroll
  for (int n = 0; n < 4; ++n) {
    const size_t col = col_blk + wn * 64 + n * 16 + p;
    const float bv = bias[col];
#pragma unroll
    for (int m = 0; m < 8; ++m) {
      const size_t row0 = row_blk + wm * 128 + m * 16 + ql * 4;
#pragma unroll
      for (int j = 0; j < 4; ++j) {
        float v = acc[m][n][j] * unscale + bv;
        const size_t o = (row0 + j) * (size_t)ldc + col;
        if constexpr (ACT == 0) {
          float r = fmaxf(v, 0.f) * 64.f;
          __half hh = __float2half(r);
          Co[o] = hh;
          Co[o + 1024] = __float2half(r - __half2float(hh));
        } else {
          float sp = fmaxf(v, 0.f) + log1pf(expf(-fabsf(v)));  // stable softplus
          Cf[o] = sp + 1e-6f;
        }
      }
    }
  }
}

__global__ __launch_bounds__(512, 2)
void gemm8p_relu(const __half* __restrict__ A, const __half* __restrict__ B,
                 const float* __restrict__ bias, __half* __restrict__ Co, int ldc) {
  gemm8p_body<0>(A, B, bias, Co, nullptr, ldc);
}

__global__ __launch_bounds__(512, 2)
void gemm8p_soft(const __half* __restrict__ A, const __half* __restrict__ B,
                 const float* __restrict__ bias, float* __restrict__ Cf, int ldc) {
  gemm8p_body<1>(A, B, bias, nullptr, Cf, ldc);
}

// ---- K4: per-row piecewise-linear inverse + jacobian (np-order-matched) ------
__global__ __launch_bounds__(256)
void pwl_epilogue(const float* __restrict__ y, const float* __restrict__ q,
                  float* __restrict__ out, int row0, int nrows) {
  const int wave = threadIdx.x >> 6, lane = threadIdx.x & 63;
  const int r = blockIdx.x * 4 + wave;
  if (r >= nrows) return;
  const float* yr = y + (size_t)(row0 + r) * 17;
  float* orow = out + (size_t)(row0 + r) * 17;
  const float* qr = q + (size_t)r * QCOLS;
  float prod_inv = 1.f;
#pragma unroll
  for (int t = 0; t < 8; ++t) {
    const float qv = qr[t * 64 + lane];
    float s = qv;
#pragma unroll
    for (int d = 1; d < 64; d <<= 1) {
      float u = __shfl_up(s, d);
      if (lane >= d) s += u;
    }
    const float total = __shfl(s, 63);
    const float sn = s / total;
    const float dnorm = total * 0.015625f;
    const float slope_l = qv / dnorm;
    const float yb = yr[8 + t];
    const unsigned long long m = __ballot(sn < yb);
    int bin = (int)__popcll(m);
    bin = bin > 63 ? 63 : bin;
    const float off_g = __shfl(sn, bin > 0 ? bin - 1 : 0);
    const float off = (bin == 0) ? 0.f : off_g;
    const float sl = __shfl(slope_l, bin);
    const float xB = (yb - off) / sl + (float)bin * 0.015625f;
    if (lane == t) orow[8 + t] = xB;
    prod_inv *= (1.f / sl);
  }
  if (lane < 8) orow[lane] = yr[lane];
  if (lane == 8) orow[16] = yr[16] * prod_inv;
}

// ---- launch ------------------------------------------------------------------
extern "C" void kernel_launch(void* const* d_in, const int* in_sizes, int n_in,
                              void* d_out, int out_size, void* d_ws, size_t ws_size,
                              hipStream_t stream) {
  const float* y  = (const float*)d_in[0];
  const float* w1 = (const float*)d_in[1];
  const float* b1 = (const float*)d_in[2];
  const float* w2 = (const float*)d_in[3];
  const float* b2 = (const float*)d_in[4];
  const float* w3 = (const float*)d_in[5];
  const float* b3 = (const float*)d_in[6];
  float* out = (float*)d_out;
  const long Btot = in_sizes[0] / 17;

  char* ws = (char*)d_ws;
  __half* w2t = (__half*)ws;                      // 4 MB  [1024][2048] hi|lo
  __half* w3t = (__half*)(ws + (4u << 20));       // 2 MB  [512][2048]  hi|lo
  const size_t fixed = (size_t)6 << 20;

  size_t avail = ws_size > fixed ? ws_size - fixed : 0;
  long maxrows = (long)(avail / 8192);
  long chunk = Btot < maxrows ? Btot : maxrows;
  chunk &= ~255L;
  if (chunk < 256) chunk = 256;

  __half* h1buf = (__half*)(ws + fixed);
  __half* h2buf = (__half*)(ws + fixed + (size_t)chunk * 4096);
  float* qbuf = (float*)h1buf;

  dim3 tb(32, 8);
  tconv_split<<<dim3(HID / 32, HID / 32), tb, 0, stream>>>(w2, w2t, HID, HID, 256.f);
  tconv_split<<<dim3(QCOLS / 32, HID / 32), tb, 0, stream>>>(w3, w3t, HID, QCOLS, 256.f);

  for (long row0 = 0; row0 < Btot; row0 += chunk) {
    const int nr = (int)((Btot - row0 < chunk) ? (Btot - row0) : chunk);
    h1_split_v2<<<(nr + 1) / 2, 256, 0, stream>>>(y, w1, b1, h1buf, (int)row0, nr);
    gemm8p_relu<<<dim3(HID / 256, nr / 256), 512, 0, stream>>>(h1buf, w2t, b2, h2buf, KP);
    gemm8p_soft<<<dim3(QCOLS / 256, nr / 256), 512, 0, stream>>>(h2buf, w3t, b3, qbuf, QCOLS);
    pwl_epilogue<<<(nr + 3) / 4, 256, 0, stream>>>(y, qbuf, out, (int)row0, nr);
  }
}